// Round 12
// baseline (803.872 us; speedup 1.0000x reference)
//
#include <hip/hip_runtime.h>

// B=1024, T=128, LAT=128, HODE=128, HID=256, OUT=128, NC=2, H=64.
// d_out = xs [128,1024,128] f32 ++ lstm_out [1024,2] f32.
//
// Structure (R12):
//   wf   : fuse l2h*h2o -> Wf (bf16) + bfused
//   ode  : per-block RK4 chains + fused projection (xs) + FUSED XW epilogue
//   lstm : 4-wave chain, ONE GATE PER LANE (quad owns a unit) — 32 fdot2/lane,
//          32 VGPR weights; gather via shfl_xor(1,2,3); 1 barrier/step
//   fc2  : tiny epilogue

typedef short s16x8 __attribute__((ext_vector_type(8)));
typedef float f32x4 __attribute__((ext_vector_type(4)));
typedef _Float16 f16x2 __attribute__((ext_vector_type(2)));
typedef _Float16 f16x8 __attribute__((ext_vector_type(8)));

#define MFMA16(a, b, c) __builtin_amdgcn_mfma_f32_16x16x32_bf16((a), (b), (c), 0, 0, 0)

// Barrier that waits only on LDS ops (lgkmcnt), NOT vmcnt (keeps global ops in flight).
__device__ __forceinline__ void lds_barrier() {
  asm volatile("s_waitcnt lgkmcnt(0)\n\ts_barrier" ::: "memory");
}

__device__ __forceinline__ unsigned short f2bf(float x) {
  union { float f; unsigned u; } v; v.f = x;
  return (unsigned short)((v.u + 0x7FFFu + ((v.u >> 16) & 1u)) >> 16);  // RNE
}

// XOR-swizzled LDS byte offset for a [rows][128] bf16 tile (row stride 256B).
__device__ __forceinline__ int swz(int row, int col2) {
  return row * 256 + (col2 ^ ((row & 7) << 4));
}

__device__ __forceinline__ f16x8 cvt8(const float* p) {
  float4 a = *(const float4*)p, b = *(const float4*)(p + 4);
  return (f16x8){(_Float16)a.x, (_Float16)a.y, (_Float16)a.z, (_Float16)a.w,
                 (_Float16)b.x, (_Float16)b.y, (_Float16)b.z, (_Float16)b.w};
}

// ---------------------------------------------------------------------------
// Kernel 1: Wf[o][k] = sum_h h2o[o][h]*l2h[h][k]; bfused[o] = h2o[o].l2h_b + h2o_b[o]
// ---------------------------------------------------------------------------
__global__ __launch_bounds__(128) void wf_kernel(
    const float* __restrict__ h2o, const float* __restrict__ l2h,
    const float* __restrict__ l2hb, const float* __restrict__ h2ob,
    unsigned short* __restrict__ wfo, float* __restrict__ bfo)
{
  const int o = (int)blockIdx.x, k = (int)threadIdx.x;
  float acc = 0.f;
  for (int h = 0; h < 256; ++h) acc = fmaf(h2o[o * 256 + h], l2h[h * 128 + k], acc);
  wfo[o * 128 + k] = f2bf(acc);
  __shared__ float red[128];
  red[k] = h2o[o * 256 + k] * l2hb[k] + h2o[o * 256 + 128 + k] * l2hb[128 + k];
  __syncthreads();
  for (int s = 64; s > 0; s >>= 1) {
    if (k < s) red[k] += red[k + s];
    __syncthreads();
  }
  if (k == 0) bfo[o] = red[0] + h2ob[o];
}

// ---------------------------------------------------------------------------
// Kernel 2: RK4 ODE + fused projection + fused XW epilogue.
// 64 blocks x 16 rows, 256 thr (4 waves).
// ---------------------------------------------------------------------------
__global__ __launch_bounds__(256, 1) void ode_kernel(
    const float* __restrict__ init, const float* __restrict__ ts,
    const float* __restrict__ w1, const float* __restrict__ b1,
    const float* __restrict__ w2, const float* __restrict__ b2,
    const unsigned short* __restrict__ wf, const float* __restrict__ bfv_,
    const float* __restrict__ wih, const float* __restrict__ bih,
    const float* __restrict__ bhh,
    float* __restrict__ xs, float* __restrict__ XW4)
{
  __shared__ __align__(16) unsigned char sY[4096];  // 16 x 128 bf16, swizzled
  __shared__ __align__(16) unsigned char sH[4096];
  __shared__ __align__(16) float sYf[2048];         // 16 x 128 f32 (XW epilogue)
  const int tid = (int)threadIdx.x;
  const int w = tid >> 6, lane = tid & 63;
  const int l15 = lane & 15, l4 = lane >> 4;
  const int rowbase = (int)blockIdx.x * 16;
  const int colbase = w * 32;

  s16x8 w1f[2][4], w2f[2][4], wff[2][4];
#pragma unroll
  for (int tc = 0; tc < 2; ++tc) {
    const int rj = colbase + 16 * tc + l15;
#pragma unroll
    for (int ks = 0; ks < 4; ++ks) {
      const int kb = ks * 32 + l4 * 8;
      s16x8 va, vb;
#pragma unroll
      for (int t = 0; t < 8; ++t) {
        va[t] = (short)f2bf(w1[rj * 128 + kb + t]);
        vb[t] = (short)f2bf(w2[rj * 128 + kb + t]);
      }
      w1f[tc][ks] = va; w2f[tc][ks] = vb;
      wff[tc][ks] = *(const s16x8*)(wf + rj * 128 + kb);
    }
  }
  float b1v[2], b2v[2], bv[2];
#pragma unroll
  for (int tc = 0; tc < 2; ++tc) {
    const int cc = colbase + 16 * tc + l15;
    b1v[tc] = b1[cc]; b2v[tc] = b2[cc]; bv[tc] = bfv_[cc];
  }

  int aOff[4];
#pragma unroll
  for (int ks = 0; ks < 4; ++ks) aOff[ks] = swz(l15, (ks * 32 + l4 * 8) * 2);
  int cOff[2][4];
#pragma unroll
  for (int tc = 0; tc < 2; ++tc)
#pragma unroll
    for (int r = 0; r < 4; ++r)
      cOff[tc][r] = swz(l4 * 4 + r, (colbase + 16 * tc + l15) * 2);

  float y0[2][4], yac[2][4];
#pragma unroll
  for (int tc = 0; tc < 2; ++tc)
#pragma unroll
    for (int r = 0; r < 4; ++r)
      y0[tc][r] = init[(rowbase + l4 * 4 + r) * 128 + colbase + 16 * tc + l15];

  {
    const int i = tid * 8;
    const int row = i >> 7, col = i & 127;
    union { unsigned short u[8]; s16x8 v; } p;
#pragma unroll
    for (int t = 0; t < 8; ++t) p.u[t] = f2bf(init[(rowbase + row) * 128 + col + t]);
    *(s16x8*)(sY + swz(row, col * 2)) = p.v;
  }
  __syncthreads();

  float* xsp = xs + (long)(rowbase + l4 * 4) * 128 + colbase + l15;
  const f32x4 fz = {0.f, 0.f, 0.f, 0.f};

  for (int s = 0; s < 127; ++s) {
    const float dt = ts[s + 1] - ts[s];
    const float c16 = dt * (1.f / 6.f), c13 = dt * (1.f / 3.f), ch = dt * 0.5f;
#pragma unroll
    for (int st = 0; st < 4; ++st) {
      f32x4 acc[2];
      acc[0] = fz; acc[1] = fz;
      if (st == 0) {
        s16x8 a[4];
#pragma unroll
        for (int ks = 0; ks < 4; ++ks) a[ks] = *(const s16x8*)(sY + aOff[ks]);
        f32x4 pa[2];
        pa[0] = fz; pa[1] = fz;
#pragma unroll
        for (int ks = 0; ks < 4; ++ks) {
          acc[0] = MFMA16(a[ks], w1f[0][ks], acc[0]);
          acc[1] = MFMA16(a[ks], w1f[1][ks], acc[1]);
          pa[0] = MFMA16(a[ks], wff[0][ks], pa[0]);
          pa[1] = MFMA16(a[ks], wff[1][ks], pa[1]);
        }
#pragma unroll
        for (int tc = 0; tc < 2; ++tc)
#pragma unroll
          for (int r = 0; r < 4; ++r)
            xsp[r * 128 + tc * 16] = pa[tc][r] + bv[tc];
        xsp += 131072;
      } else {
#pragma unroll
        for (int ks = 0; ks < 4; ++ks) {
          s16x8 a = *(const s16x8*)(sY + aOff[ks]);
          acc[0] = MFMA16(a, w1f[0][ks], acc[0]);
          acc[1] = MFMA16(a, w1f[1][ks], acc[1]);
        }
      }
#pragma unroll
      for (int tc = 0; tc < 2; ++tc)
#pragma unroll
        for (int r = 0; r < 4; ++r) {
          float v = acc[tc][r] + b1v[tc];
          v = v > 0.f ? v : (__expf(v) - 1.f);  // ELU (alpha=1)
          *(unsigned short*)(sH + cOff[tc][r]) = f2bf(v);
        }
      lds_barrier();
      f32x4 kc[2];
      kc[0] = fz; kc[1] = fz;
#pragma unroll
      for (int ks = 0; ks < 4; ++ks) {
        s16x8 a = *(const s16x8*)(sH + aOff[ks]);
        kc[0] = MFMA16(a, w2f[0][ks], kc[0]);
        kc[1] = MFMA16(a, w2f[1][ks], kc[1]);
      }
#pragma unroll
      for (int tc = 0; tc < 2; ++tc)
#pragma unroll
        for (int r = 0; r < 4; ++r) {
          const float kv = kc[tc][r] + b2v[tc];
          float yn;
          if (st == 0)      { yac[tc][r] = fmaf(c16, kv, y0[tc][r]);  yn = fmaf(ch, kv, y0[tc][r]); }
          else if (st == 1) { yac[tc][r] = fmaf(c13, kv, yac[tc][r]); yn = fmaf(ch, kv, y0[tc][r]); }
          else if (st == 2) { yac[tc][r] = fmaf(c13, kv, yac[tc][r]); yn = fmaf(dt, kv, y0[tc][r]); }
          else              { y0[tc][r]  = fmaf(c16, kv, yac[tc][r]); yn = y0[tc][r]; }
          *(unsigned short*)(sY + cOff[tc][r]) = f2bf(yn);
        }
      lds_barrier();
    }
  }
  {  // epilogue A: xs[127] = proj(y_127)
    f32x4 pa[2];
    pa[0] = fz; pa[1] = fz;
#pragma unroll
    for (int ks = 0; ks < 4; ++ks) {
      s16x8 a = *(const s16x8*)(sY + aOff[ks]);
      pa[0] = MFMA16(a, wff[0][ks], pa[0]);
      pa[1] = MFMA16(a, wff[1][ks], pa[1]);
    }
#pragma unroll
    for (int tc = 0; tc < 2; ++tc)
#pragma unroll
      for (int r = 0; r < 4; ++r)
        xsp[r * 128 + tc * 16] = pa[tc][r] + bv[tc];
  }
  // epilogue B: XW4 for this block's 16 t's (bit-identical to old xw_kernel)
#pragma unroll
  for (int tc = 0; tc < 2; ++tc)
#pragma unroll
    for (int r = 0; r < 4; ++r)
      sYf[(l4 * 4 + r) * 128 + colbase + 16 * tc + l15] = y0[tc][r];
  lds_barrier();
  {
    const int g = tid;                     // 0..255 (gate row)
    const int q = g >> 6, j = g & 63;
#pragma unroll 4
    for (int tl = 0; tl < 16; ++tl) {
      float a0 = 0.f, a1 = 0.f, a2 = 0.f, a3 = 0.f;
#pragma unroll 8
      for (int k = 0; k < 32; ++k) {
        float4 wv = *(const float4*)(wih + g * 128 + 4 * k);
        float4 yv = *(const float4*)(sYf + tl * 128 + 4 * k);
        a0 = fmaf(wv.x, yv.x, a0); a1 = fmaf(wv.y, yv.y, a1);
        a2 = fmaf(wv.z, yv.z, a2); a3 = fmaf(wv.w, yv.w, a3);
      }
      XW4[(rowbase + tl) * 256 + j * 4 + q] = bih[g] + bhh[g] + ((a0 + a1) + (a2 + a3));
    }
  }
}

// ---------------------------------------------------------------------------
// Kernel 3: LSTM chain — 4 waves, ONE GATE PER LANE.
// Lane quad (L&~3 .. |3) owns unit j = wave*16 + (L>>2); gate q = L&3
// (0:i 1:f 2:g 3:o). 32 fdot2/lane; gather via shfl_xor(1,2,3);
// all 4 lanes redundantly update c,h; q==0 writes. One barrier/step.
// ---------------------------------------------------------------------------
__global__ __launch_bounds__(256, 1) void lstm_kernel(
    const float* __restrict__ XW4,   // [1024][64*4] (j*4+q)
    const float* __restrict__ whh,   // [256][64] f32
    float* __restrict__ hsT)         // [64][1024]
{
  const int tid = (int)threadIdx.x;  // 0..255
  const int L = tid & 63;
  const int q = L & 3;
  const int j = (tid >> 6) * 16 + (L >> 2);
  const int row = q * 64 + j;

  __shared__ __align__(16) _Float16 hbuf[2][64];

  f16x8 wq[8];                       // 64 f16 = 32 VGPR
#pragma unroll
  for (int k = 0; k < 8; ++k) wq[k] = cvt8(whh + row * 64 + 8 * k);

  // unified activation: act = A * rcp(1 + exp(S*x)) + B ; q==2 (g) is tanh
  const float Aa = (q == 2) ? 2.f : 1.f;
  const float Sa = (q == 2) ? -2.f : -1.f;
  const float Ba = (q == 2) ? -1.f : 0.f;

  if (tid < 64) hbuf[0][tid] = (_Float16)0.f;
  float c = 0.f;

  const int xwi = j * 4 + q;
  float xq[4];
#pragma unroll
  for (int i = 0; i < 4; ++i) xq[i] = XW4[i * 256 + xwi];
  lds_barrier();

  for (int tb = 0; tb < 256; ++tb) {
#pragma unroll
    for (int i = 0; i < 4; ++i) {
      const int t = tb * 4 + i;
      const int cur = i & 1;               // == t & 1
      const float xw = xq[i];
      xq[i] = XW4[((t + 4) & 1023) * 256 + xwi];  // prefetch 4 steps ahead

      const f16x8* hb8 = (const f16x8*)hbuf[cur];
      float4 ac = {0.f, 0.f, 0.f, 0.f};
#pragma unroll
      for (int r = 0; r < 8; ++r) {
        const f16x8 v = hb8[r];            // broadcast ds_read_b128
        ac.x = __builtin_amdgcn_fdot2(__builtin_shufflevector(wq[r], wq[r], 0, 1),
                                      __builtin_shufflevector(v, v, 0, 1), ac.x, false);
        ac.y = __builtin_amdgcn_fdot2(__builtin_shufflevector(wq[r], wq[r], 2, 3),
                                      __builtin_shufflevector(v, v, 2, 3), ac.y, false);
        ac.z = __builtin_amdgcn_fdot2(__builtin_shufflevector(wq[r], wq[r], 4, 5),
                                      __builtin_shufflevector(v, v, 4, 5), ac.z, false);
        ac.w = __builtin_amdgcn_fdot2(__builtin_shufflevector(wq[r], wq[r], 6, 7),
                                      __builtin_shufflevector(v, v, 6, 7), ac.w, false);
      }
      const float pre = xw + ((ac.x + ac.y) + (ac.z + ac.w));
      const float act = fmaf(Aa, __builtin_amdgcn_rcpf(1.f + __expf(Sa * pre)), Ba);

      // gather quad's 4 gates (value from shfl_xor(m) is gate q^m)
      const float x1 = __shfl_xor(act, 1);
      const float x2 = __shfl_xor(act, 2);
      const float x3 = __shfl_xor(act, 3);
      const float gi = (q == 0) ? act : (q == 1) ? x1 : (q == 2) ? x2 : x3;
      const float gf = (q == 0) ? x1 : (q == 1) ? act : (q == 2) ? x3 : x2;
      const float gg = (q == 0) ? x2 : (q == 1) ? x3 : (q == 2) ? act : x1;
      const float go = (q == 0) ? x3 : (q == 1) ? x2 : (q == 2) ? x1 : act;

      c = fmaf(gf, c, gi * gg);            // identical in all 4 quad lanes
      const float th = fmaf(2.f, __builtin_amdgcn_rcpf(1.f + __expf(-2.f * c)), -1.f);
      const float h = go * th;

      if (q == 0) {
        hbuf[cur ^ 1][j] = (_Float16)h;    // next step's broadcast source
        hsT[j * 1024 + t] = h;
      }
      lds_barrier();                       // ONE barrier per step
    }
  }
}

// ---------------------------------------------------------------------------
// Kernel 4: lstm_out[t][n] = fc2_w[n] . h_t + fc2_b[n]
// ---------------------------------------------------------------------------
__global__ __launch_bounds__(256) void fc2_kernel(
    const float* __restrict__ hsT, const float* __restrict__ fw,
    const float* __restrict__ fb, float* __restrict__ lout)
{
  const int idx = (int)blockIdx.x * 256 + (int)threadIdx.x;  // 0..2047
  const int n = idx >> 10, t = idx & 1023;
  float acc = fb[n];
#pragma unroll 8
  for (int j = 0; j < 64; ++j) acc = fmaf(fw[n * 64 + j], hsT[j * 1024 + t], acc);
  lout[t * 2 + n] = acc;
}

// ---------------------------------------------------------------------------
extern "C" void kernel_launch(void* const* d_in, const int* in_sizes, int n_in,
                              void* d_out, int out_size, void* d_ws, size_t ws_size,
                              hipStream_t stream) {
  const float* init  = (const float*)d_in[0];
  const float* ts    = (const float*)d_in[1];
  const float* ode_w1 = (const float*)d_in[2];
  const float* ode_b1 = (const float*)d_in[3];
  const float* ode_w2 = (const float*)d_in[4];
  const float* ode_b2 = (const float*)d_in[5];
  const float* l2h_w = (const float*)d_in[6];
  const float* l2h_b = (const float*)d_in[7];
  const float* h2o_w = (const float*)d_in[8];
  const float* h2o_b = (const float*)d_in[9];
  const float* wih   = (const float*)d_in[10];
  const float* whh   = (const float*)d_in[11];
  const float* bih   = (const float*)d_in[12];
  const float* bhh   = (const float*)d_in[13];
  const float* fc2w  = (const float*)d_in[14];
  const float* fc2b  = (const float*)d_in[15];

  char* ws = (char*)d_ws;
  float* XW4            = (float*)(ws);                        // 1,048,576 B
  float* hsT            = (float*)(ws + 1048576);              //   262,144 B
  unsigned short* wfbuf = (unsigned short*)(ws + 1310720);     //    32,768 B
  float* bfused         = (float*)(ws + 1343488);              //       512 B

  float* xs   = (float*)d_out;
  float* lout = xs + 16777216;

  wf_kernel<<<128, 128, 0, stream>>>(h2o_w, l2h_w, l2h_b, h2o_b, wfbuf, bfused);
  ode_kernel<<<64, 256, 0, stream>>>(init, ts, ode_w1, ode_b1, ode_w2, ode_b2,
                                     wfbuf, bfused, wih, bih, bhh, xs, XW4);
  lstm_kernel<<<1, 256, 0, stream>>>(XW4, whh, hsT);
  fc2_kernel<<<8, 256, 0, stream>>>(hsT, fc2w, fc2b, lout);
}

// Round 13
// 701.283 us; speedup vs baseline: 1.1463x; 1.1463x over previous
//
#include <hip/hip_runtime.h>

// B=1024, T=128, LAT=128, HODE=128, HID=256, OUT=128, NC=2, H=64.
// d_out = xs [128,1024,128] f32 ++ lstm_out [1024,2] f32.
//
// Structure (R13):
//   wf   : fuse l2h*h2o -> Wf (bf16) + bfused
//   ode  : RK4 chains + fused projection (xs) + fused XW epilogue
//          R13: v_cvt_pk_bf16_f32 packing on the critical path (RNE, bit-identical)
//   lstm : 4-wave chain, one gate per lane (quad owns a unit)
//          R13: gate gather via DPP quad_perm (VALU, ~2cyc) instead of shfl/ds_bpermute
//   fc2  : tiny epilogue

typedef short s16x8 __attribute__((ext_vector_type(8)));
typedef float f32x4 __attribute__((ext_vector_type(4)));
typedef _Float16 f16x2 __attribute__((ext_vector_type(2)));
typedef _Float16 f16x8 __attribute__((ext_vector_type(8)));

#define MFMA16(a, b, c) __builtin_amdgcn_mfma_f32_16x16x32_bf16((a), (b), (c), 0, 0, 0)

// Barrier that waits only on LDS ops (lgkmcnt), NOT vmcnt (keeps global ops in flight).
__device__ __forceinline__ void lds_barrier() {
  asm volatile("s_waitcnt lgkmcnt(0)\n\ts_barrier" ::: "memory");
}

__device__ __forceinline__ unsigned short f2bf(float x) {
  union { float f; unsigned u; } v; v.f = x;
  return (unsigned short)((v.u + 0x7FFFu + ((v.u >> 16) & 1u)) >> 16);  // RNE
}

// Pack 2 f32 -> 2 bf16 in one dword (RNE; bit-identical to f2bf for finite vals).
__device__ __forceinline__ unsigned cvtpk(float lo, float hi) {
  unsigned r;
  asm("v_cvt_pk_bf16_f32 %0, %1, %2" : "=v"(r) : "v"(lo), "v"(hi));
  return r;
}

// XOR-swizzled LDS byte offset for a [rows][128] bf16 tile (row stride 256B).
__device__ __forceinline__ int swz(int row, int col2) {
  return row * 256 + (col2 ^ ((row & 7) << 4));
}

__device__ __forceinline__ f16x8 cvt8(const float* p) {
  float4 a = *(const float4*)p, b = *(const float4*)(p + 4);
  return (f16x8){(_Float16)a.x, (_Float16)a.y, (_Float16)a.z, (_Float16)a.w,
                 (_Float16)b.x, (_Float16)b.y, (_Float16)b.z, (_Float16)b.w};
}

// ---------------------------------------------------------------------------
// Kernel 1: Wf[o][k] = sum_h h2o[o][h]*l2h[h][k]; bfused[o] = h2o[o].l2h_b + h2o_b[o]
// ---------------------------------------------------------------------------
__global__ __launch_bounds__(128) void wf_kernel(
    const float* __restrict__ h2o, const float* __restrict__ l2h,
    const float* __restrict__ l2hb, const float* __restrict__ h2ob,
    unsigned short* __restrict__ wfo, float* __restrict__ bfo)
{
  const int o = (int)blockIdx.x, k = (int)threadIdx.x;
  float acc = 0.f;
  for (int h = 0; h < 256; ++h) acc = fmaf(h2o[o * 256 + h], l2h[h * 128 + k], acc);
  wfo[o * 128 + k] = f2bf(acc);
  __shared__ float red[128];
  red[k] = h2o[o * 256 + k] * l2hb[k] + h2o[o * 256 + 128 + k] * l2hb[128 + k];
  __syncthreads();
  for (int s = 64; s > 0; s >>= 1) {
    if (k < s) red[k] += red[k + s];
    __syncthreads();
  }
  if (k == 0) bfo[o] = red[0] + h2ob[o];
}

// ---------------------------------------------------------------------------
// Kernel 2: RK4 ODE + fused projection + fused XW epilogue.
// 64 blocks x 16 rows, 256 thr (4 waves).
// ---------------------------------------------------------------------------
__global__ __launch_bounds__(256, 1) void ode_kernel(
    const float* __restrict__ init, const float* __restrict__ ts,
    const float* __restrict__ w1, const float* __restrict__ b1,
    const float* __restrict__ w2, const float* __restrict__ b2,
    const unsigned short* __restrict__ wf, const float* __restrict__ bfv_,
    const float* __restrict__ wih, const float* __restrict__ bih,
    const float* __restrict__ bhh,
    float* __restrict__ xs, float* __restrict__ XW4)
{
  __shared__ __align__(16) unsigned char sY[4096];  // 16 x 128 bf16, swizzled
  __shared__ __align__(16) unsigned char sH[4096];
  __shared__ __align__(16) float sYf[2048];         // 16 x 128 f32 (XW epilogue)
  const int tid = (int)threadIdx.x;
  const int w = tid >> 6, lane = tid & 63;
  const int l15 = lane & 15, l4 = lane >> 4;
  const int rowbase = (int)blockIdx.x * 16;
  const int colbase = w * 32;

  s16x8 w1f[2][4], w2f[2][4], wff[2][4];
#pragma unroll
  for (int tc = 0; tc < 2; ++tc) {
    const int rj = colbase + 16 * tc + l15;
#pragma unroll
    for (int ks = 0; ks < 4; ++ks) {
      const int kb = ks * 32 + l4 * 8;
      s16x8 va, vb;
#pragma unroll
      for (int t = 0; t < 8; ++t) {
        va[t] = (short)f2bf(w1[rj * 128 + kb + t]);
        vb[t] = (short)f2bf(w2[rj * 128 + kb + t]);
      }
      w1f[tc][ks] = va; w2f[tc][ks] = vb;
      wff[tc][ks] = *(const s16x8*)(wf + rj * 128 + kb);
    }
  }
  float b1v[2], b2v[2], bv[2];
#pragma unroll
  for (int tc = 0; tc < 2; ++tc) {
    const int cc = colbase + 16 * tc + l15;
    b1v[tc] = b1[cc]; b2v[tc] = b2[cc]; bv[tc] = bfv_[cc];
  }

  int aOff[4];
#pragma unroll
  for (int ks = 0; ks < 4; ++ks) aOff[ks] = swz(l15, (ks * 32 + l4 * 8) * 2);
  int cOff[2][4];
#pragma unroll
  for (int tc = 0; tc < 2; ++tc)
#pragma unroll
    for (int r = 0; r < 4; ++r)
      cOff[tc][r] = swz(l4 * 4 + r, (colbase + 16 * tc + l15) * 2);

  float y0[2][4], yac[2][4];
#pragma unroll
  for (int tc = 0; tc < 2; ++tc)
#pragma unroll
    for (int r = 0; r < 4; ++r)
      y0[tc][r] = init[(rowbase + l4 * 4 + r) * 128 + colbase + 16 * tc + l15];

  {
    const int i = tid * 8;
    const int row = i >> 7, col = i & 127;
    union { unsigned short u[8]; s16x8 v; } p;
#pragma unroll
    for (int t = 0; t < 8; ++t) p.u[t] = f2bf(init[(rowbase + row) * 128 + col + t]);
    *(s16x8*)(sY + swz(row, col * 2)) = p.v;
  }
  __syncthreads();

  float* xsp = xs + (long)(rowbase + l4 * 4) * 128 + colbase + l15;
  const f32x4 fz = {0.f, 0.f, 0.f, 0.f};

  for (int s = 0; s < 127; ++s) {
    const float dt = ts[s + 1] - ts[s];
    const float c16 = dt * (1.f / 6.f), c13 = dt * (1.f / 3.f), ch = dt * 0.5f;
#pragma unroll
    for (int st = 0; st < 4; ++st) {
      f32x4 acc[2];
      acc[0] = fz; acc[1] = fz;
      if (st == 0) {
        s16x8 a[4];
#pragma unroll
        for (int ks = 0; ks < 4; ++ks) a[ks] = *(const s16x8*)(sY + aOff[ks]);
        f32x4 pa[2];
        pa[0] = fz; pa[1] = fz;
#pragma unroll
        for (int ks = 0; ks < 4; ++ks) {
          acc[0] = MFMA16(a[ks], w1f[0][ks], acc[0]);
          acc[1] = MFMA16(a[ks], w1f[1][ks], acc[1]);
          pa[0] = MFMA16(a[ks], wff[0][ks], pa[0]);
          pa[1] = MFMA16(a[ks], wff[1][ks], pa[1]);
        }
#pragma unroll
        for (int tc = 0; tc < 2; ++tc)
#pragma unroll
          for (int r = 0; r < 4; ++r)
            xsp[r * 128 + tc * 16] = pa[tc][r] + bv[tc];
        xsp += 131072;
      } else {
#pragma unroll
        for (int ks = 0; ks < 4; ++ks) {
          s16x8 a = *(const s16x8*)(sY + aOff[ks]);
          acc[0] = MFMA16(a, w1f[0][ks], acc[0]);
          acc[1] = MFMA16(a, w1f[1][ks], acc[1]);
        }
      }
      // bias + ELU + packed bf16 store (cvt_pk on the critical path)
#pragma unroll
      for (int r = 0; r < 4; ++r) {
        float v0 = acc[0][r] + b1v[0];
        float v1 = acc[1][r] + b1v[1];
        v0 = v0 > 0.f ? v0 : (__expf(v0) - 1.f);  // ELU (alpha=1)
        v1 = v1 > 0.f ? v1 : (__expf(v1) - 1.f);
        const unsigned p = cvtpk(v0, v1);
        *(unsigned short*)(sH + cOff[0][r]) = (unsigned short)p;
        *(unsigned short*)(sH + cOff[1][r]) = (unsigned short)(p >> 16);
      }
      lds_barrier();
      f32x4 kc[2];
      kc[0] = fz; kc[1] = fz;
#pragma unroll
      for (int ks = 0; ks < 4; ++ks) {
        s16x8 a = *(const s16x8*)(sH + aOff[ks]);
        kc[0] = MFMA16(a, w2f[0][ks], kc[0]);
        kc[1] = MFMA16(a, w2f[1][ks], kc[1]);
      }
#pragma unroll
      for (int r = 0; r < 4; ++r) {
        float yn2[2];
#pragma unroll
        for (int tc = 0; tc < 2; ++tc) {
          const float kv = kc[tc][r] + b2v[tc];
          float yn;
          if (st == 0)      { yac[tc][r] = fmaf(c16, kv, y0[tc][r]);  yn = fmaf(ch, kv, y0[tc][r]); }
          else if (st == 1) { yac[tc][r] = fmaf(c13, kv, yac[tc][r]); yn = fmaf(ch, kv, y0[tc][r]); }
          else if (st == 2) { yac[tc][r] = fmaf(c13, kv, yac[tc][r]); yn = fmaf(dt, kv, y0[tc][r]); }
          else              { y0[tc][r]  = fmaf(c16, kv, yac[tc][r]); yn = y0[tc][r]; }
          yn2[tc] = yn;
        }
        const unsigned p = cvtpk(yn2[0], yn2[1]);
        *(unsigned short*)(sY + cOff[0][r]) = (unsigned short)p;
        *(unsigned short*)(sY + cOff[1][r]) = (unsigned short)(p >> 16);
      }
      lds_barrier();
    }
  }
  {  // epilogue A: xs[127] = proj(y_127)
    f32x4 pa[2];
    pa[0] = fz; pa[1] = fz;
#pragma unroll
    for (int ks = 0; ks < 4; ++ks) {
      s16x8 a = *(const s16x8*)(sY + aOff[ks]);
      pa[0] = MFMA16(a, wff[0][ks], pa[0]);
      pa[1] = MFMA16(a, wff[1][ks], pa[1]);
    }
#pragma unroll
    for (int tc = 0; tc < 2; ++tc)
#pragma unroll
      for (int r = 0; r < 4; ++r)
        xsp[r * 128 + tc * 16] = pa[tc][r] + bv[tc];
  }
  // epilogue B: XW4 for this block's 16 t's (bit-identical to old xw_kernel)
#pragma unroll
  for (int tc = 0; tc < 2; ++tc)
#pragma unroll
    for (int r = 0; r < 4; ++r)
      sYf[(l4 * 4 + r) * 128 + colbase + 16 * tc + l15] = y0[tc][r];
  lds_barrier();
  {
    const int g = tid;                     // 0..255 (gate row)
    const int q = g >> 6, j = g & 63;
#pragma unroll 4
    for (int tl = 0; tl < 16; ++tl) {
      float a0 = 0.f, a1 = 0.f, a2 = 0.f, a3 = 0.f;
#pragma unroll 8
      for (int k = 0; k < 32; ++k) {
        float4 wv = *(const float4*)(wih + g * 128 + 4 * k);
        float4 yv = *(const float4*)(sYf + tl * 128 + 4 * k);
        a0 = fmaf(wv.x, yv.x, a0); a1 = fmaf(wv.y, yv.y, a1);
        a2 = fmaf(wv.z, yv.z, a2); a3 = fmaf(wv.w, yv.w, a3);
      }
      XW4[(rowbase + tl) * 256 + j * 4 + q] = bih[g] + bhh[g] + ((a0 + a1) + (a2 + a3));
    }
  }
}

// ---------------------------------------------------------------------------
// Kernel 3: LSTM chain — 4 waves, one gate per lane; gather via DPP quad_perm.
// Lane quad owns unit j = wave*16 + (L>>2); gate q = L&3 (0:i 1:f 2:g 3:o).
// ---------------------------------------------------------------------------
__global__ __launch_bounds__(256, 1) void lstm_kernel(
    const float* __restrict__ XW4,   // [1024][64*4] (j*4+q)
    const float* __restrict__ whh,   // [256][64] f32
    float* __restrict__ hsT)         // [64][1024]
{
  const int tid = (int)threadIdx.x;  // 0..255
  const int L = tid & 63;
  const int q = L & 3;
  const int j = (tid >> 6) * 16 + (L >> 2);
  const int row = q * 64 + j;

  __shared__ __align__(16) _Float16 hbuf[2][64];

  f16x8 wq[8];                       // 64 f16 = 32 VGPR
#pragma unroll
  for (int k = 0; k < 8; ++k) wq[k] = cvt8(whh + row * 64 + 8 * k);

  // unified activation: act = A * rcp(1 + exp(S*x)) + B ; q==2 (g) is tanh
  const float Aa = (q == 2) ? 2.f : 1.f;
  const float Sa = (q == 2) ? -2.f : -1.f;
  const float Ba = (q == 2) ? -1.f : 0.f;

  if (tid < 64) hbuf[0][tid] = (_Float16)0.f;
  float c = 0.f;

  const int xwi = j * 4 + q;
  float xq[4];
#pragma unroll
  for (int i = 0; i < 4; ++i) xq[i] = XW4[i * 256 + xwi];
  lds_barrier();

  for (int tb = 0; tb < 256; ++tb) {
#pragma unroll
    for (int i = 0; i < 4; ++i) {
      const int t = tb * 4 + i;
      const int cur = i & 1;               // == t & 1
      const float xw = xq[i];
      xq[i] = XW4[((t + 4) & 1023) * 256 + xwi];  // prefetch 4 steps ahead

      const f16x8* hb8 = (const f16x8*)hbuf[cur];
      float4 ac = {0.f, 0.f, 0.f, 0.f};
#pragma unroll
      for (int r = 0; r < 8; ++r) {
        const f16x8 v = hb8[r];            // broadcast ds_read_b128
        ac.x = __builtin_amdgcn_fdot2(__builtin_shufflevector(wq[r], wq[r], 0, 1),
                                      __builtin_shufflevector(v, v, 0, 1), ac.x, false);
        ac.y = __builtin_amdgcn_fdot2(__builtin_shufflevector(wq[r], wq[r], 2, 3),
                                      __builtin_shufflevector(v, v, 2, 3), ac.y, false);
        ac.z = __builtin_amdgcn_fdot2(__builtin_shufflevector(wq[r], wq[r], 4, 5),
                                      __builtin_shufflevector(v, v, 4, 5), ac.z, false);
        ac.w = __builtin_amdgcn_fdot2(__builtin_shufflevector(wq[r], wq[r], 6, 7),
                                      __builtin_shufflevector(v, v, 6, 7), ac.w, false);
      }
      const float pre = xw + ((ac.x + ac.y) + (ac.z + ac.w));
      const float act = fmaf(Aa, __builtin_amdgcn_rcpf(1.f + __expf(Sa * pre)), Ba);

      // gather quad's 4 gates via DPP quad_perm (VALU, no LDS pipe):
      // 0xB1=[1,0,3,2]=xor1, 0x4E=[2,3,0,1]=xor2, 0x1B=[3,2,1,0]=xor3
      const int ai = __float_as_int(act);
      const float x1 = __int_as_float(__builtin_amdgcn_mov_dpp(ai, 0xB1, 0xF, 0xF, true));
      const float x2 = __int_as_float(__builtin_amdgcn_mov_dpp(ai, 0x4E, 0xF, 0xF, true));
      const float x3 = __int_as_float(__builtin_amdgcn_mov_dpp(ai, 0x1B, 0xF, 0xF, true));
      const float gi = (q == 0) ? act : (q == 1) ? x1 : (q == 2) ? x2 : x3;
      const float gf = (q == 0) ? x1 : (q == 1) ? act : (q == 2) ? x3 : x2;
      const float gg = (q == 0) ? x2 : (q == 1) ? x3 : (q == 2) ? act : x1;
      const float go = (q == 0) ? x3 : (q == 1) ? x2 : (q == 2) ? x1 : act;

      c = fmaf(gf, c, gi * gg);            // identical in all 4 quad lanes
      const float th = fmaf(2.f, __builtin_amdgcn_rcpf(1.f + __expf(-2.f * c)), -1.f);
      const float h = go * th;

      if (q == 0) {
        hbuf[cur ^ 1][j] = (_Float16)h;    // next step's broadcast source
        hsT[j * 1024 + t] = h;
      }
      lds_barrier();                       // ONE barrier per step
    }
  }
}

// ---------------------------------------------------------------------------
// Kernel 4: lstm_out[t][n] = fc2_w[n] . h_t + fc2_b[n]
// ---------------------------------------------------------------------------
__global__ __launch_bounds__(256) void fc2_kernel(
    const float* __restrict__ hsT, const float* __restrict__ fw,
    const float* __restrict__ fb, float* __restrict__ lout)
{
  const int idx = (int)blockIdx.x * 256 + (int)threadIdx.x;  // 0..2047
  const int n = idx >> 10, t = idx & 1023;
  float acc = fb[n];
#pragma unroll 8
  for (int j = 0; j < 64; ++j) acc = fmaf(fw[n * 64 + j], hsT[j * 1024 + t], acc);
  lout[t * 2 + n] = acc;
}

// ---------------------------------------------------------------------------
extern "C" void kernel_launch(void* const* d_in, const int* in_sizes, int n_in,
                              void* d_out, int out_size, void* d_ws, size_t ws_size,
                              hipStream_t stream) {
  const float* init  = (const float*)d_in[0];
  const float* ts    = (const float*)d_in[1];
  const float* ode_w1 = (const float*)d_in[2];
  const float* ode_b1 = (const float*)d_in[3];
  const float* ode_w2 = (const float*)d_in[4];
  const float* ode_b2 = (const float*)d_in[5];
  const float* l2h_w = (const float*)d_in[6];
  const float* l2h_b = (const float*)d_in[7];
  const float* h2o_w = (const float*)d_in[8];
  const float* h2o_b = (const float*)d_in[9];
  const float* wih   = (const float*)d_in[10];
  const float* whh   = (const float*)d_in[11];
  const float* bih   = (const float*)d_in[12];
  const float* bhh   = (const float*)d_in[13];
  const float* fc2w  = (const float*)d_in[14];
  const float* fc2b  = (const float*)d_in[15];

  char* ws = (char*)d_ws;
  float* XW4            = (float*)(ws);                        // 1,048,576 B
  float* hsT            = (float*)(ws + 1048576);              //   262,144 B
  unsigned short* wfbuf = (unsigned short*)(ws + 1310720);     //    32,768 B
  float* bfused         = (float*)(ws + 1343488);              //       512 B

  float* xs   = (float*)d_out;
  float* lout = xs + 16777216;

  wf_kernel<<<128, 128, 0, stream>>>(h2o_w, l2h_w, l2h_b, h2o_b, wfbuf, bfused);
  ode_kernel<<<64, 256, 0, stream>>>(init, ts, ode_w1, ode_b1, ode_w2, ode_b2,
                                     wfbuf, bfused, wih, bih, bhh, xs, XW4);
  lstm_kernel<<<1, 256, 0, stream>>>(XW4, whh, hsT);
  fc2_kernel<<<8, 256, 0, stream>>>(hsT, fc2w, fc2b, lout);
}